// Round 9
// baseline (428.110 us; speedup 1.0000x reference)
//
#include <hip/hip_runtime.h>
#include <hip/hip_bf16.h>
#include <stdint.h>

#define N_NODES   65536
#define N_GRAPHS  1024
#define N_EDGES   1048576
#define IN_FEATS  512
#define HIDDEN    1024
#define H4        256
#define EMB_DIM   512
#define RDIM      1792   // 512 + 1024 + 256
#define EPS_F     1e-5f
#define SLOPE_F   0.01f

typedef __bf16 bf16;
typedef __bf16 bf16x4 __attribute__((ext_vector_type(4)));
typedef __bf16 bf16x8 __attribute__((ext_vector_type(8)));
typedef float  floatx4 __attribute__((ext_vector_type(4)));

#define GLDS16(gp, lp) __builtin_amdgcn_global_load_lds( \
    (const __attribute__((address_space(1))) void*)(gp), \
    (__attribute__((address_space(3))) void*)(lp), 16, 0, 0)

// -------------------------------------------- fused edge pass, per graph
__global__ __launch_bounds__(256) void k_graph_build(
    const int* __restrict__ src, const int* __restrict__ dst,
    const float* __restrict__ ew,
    bf16* __restrict__ adjb, float* __restrict__ scl_o)
{
    __shared__ float sAdj[4096];
    __shared__ float sDegO[64], sDegI[64];
    int g = blockIdx.x, tid = threadIdx.x;
    for (int i = tid; i < 4096; i += 256) sAdj[i] = 0.f;
    if (tid < 64) { sDegO[tid] = 0.f; sDegI[tid] = 0.f; }
    __syncthreads();
    int e0 = g * 1024;
    #pragma unroll
    for (int i = 0; i < 4; ++i) {
        int e = e0 + i * 256 + tid;
        int s = src[e] & 63, d = dst[e] & 63;
        atomicAdd(&sAdj[(d << 6) | s], ew[e]);
        atomicAdd(&sDegO[s], 1.f);
        atomicAdd(&sDegI[d], 1.f);
    }
    __syncthreads();
    if (tid < 64) scl_o[g * 64 + tid] = rsqrtf(fmaxf(sDegO[tid], 1.f));
    bf16* ag = adjb + ((size_t)g << 12);
    for (int i = tid; i < 4096; i += 256) {
        float si = rsqrtf(fmaxf(sDegI[i >> 6], 1.f));
        ag[i] = (bf16)(sAdj[i] * si);
    }
}

// ------------- single-launch tiled transpose for all three weight matrices
__global__ __launch_bounds__(256) void k_transpose3(
    const float* __restrict__ W1, bf16* __restrict__ W1T,
    const float* __restrict__ W2, bf16* __restrict__ W2T,
    const float* __restrict__ We, bf16* __restrict__ WeT)
{
    __shared__ float sT[64][65];
    int b = blockIdx.x;
    const float* W; bf16* WT; int K, N, bx, by;
    if (b < 128)      { W = W1; WT = W1T; K = 512;  N = 1024; bx = b & 7;  by = b >> 3; }
    else if (b < 192) { b -= 128; W = W2; WT = W2T; K = 1024; N = 256;  bx = b & 15; by = b >> 4; }
    else              { b -= 192; W = We; WT = WeT; K = 1792; N = 512;  bx = b % 28; by = b / 28; }
    const int k0 = bx * 64, n0 = by * 64;
    const int tid = threadIdx.x;
    const int lr = tid >> 4, lc = (tid & 15) * 4;
    #pragma unroll
    for (int i = 0; i < 4; ++i) {
        int row = lr + i * 16;
        float4 v = *(const float4*)&W[(size_t)(k0 + row) * N + n0 + lc];
        sT[row][lc + 0] = v.x; sT[row][lc + 1] = v.y;
        sT[row][lc + 2] = v.z; sT[row][lc + 3] = v.w;
    }
    __syncthreads();
    const int nn = tid >> 2, kk0 = (tid & 3) * 16;
    #pragma unroll
    for (int h = 0; h < 2; ++h) {
        bf16x8 o;
        #pragma unroll
        for (int j = 0; j < 8; ++j)
            o[j] = (bf16)sT[kk0 + h * 8 + j][nn];
        *(bf16x8*)&WT[(size_t)(n0 + nn) * K + k0 + kk0 + h * 8] = o;
    }
}

// -------------------------------------- fused prep + agg layer 1 (2 blk/graph)
__global__ __launch_bounds__(256) void k_prep_agg1(
    const float* __restrict__ x, const float* __restrict__ so,
    const bf16* __restrict__ adjb,
    bf16* __restrict__ axs1, bf16* __restrict__ Rb)
{
    __shared__ __align__(16) bf16 sXrT[256 * 64];  // xs^T [col][64], swizzled
    __shared__ __align__(16) bf16 sOut[64 * 264];
    __shared__ float sSo[64];
    int g = blockIdx.x >> 1, half = blockIdx.x & 1;
    int tid = threadIdx.x, lane = tid & 63, wave = tid >> 6, q = lane >> 4;
    if (tid < 64) sSo[tid] = so[g * 64 + tid];

    const float* xg = x + (size_t)g * 64 * IN_FEATS + half * 256;
    const bf16* ag = adjb + ((size_t)g << 12);

    bf16x8 af[4][2];
    #pragma unroll
    for (int mt = 0; mt < 4; ++mt)
        #pragma unroll
        for (int kk = 0; kk < 2; ++kk)
            af[mt][kk] = *(const bf16x8*)&ag[(mt * 16 + (lane & 15)) * 64 + kk * 32 + q * 8];
    __syncthreads();                       // sSo visible

    float r0 = 0.f;
    const int sw = tid & 7;
    #pragma unroll
    for (int r8 = 0; r8 < 8; ++r8) {
        bf16x8 p;
        #pragma unroll
        for (int j = 0; j < 8; ++j) {
            int r = r8 * 8 + j;
            float v = xg[(size_t)r * IN_FEATS + tid];
            r0 += v;
            p[j] = (bf16)(v * sSo[r]);
        }
        *(bf16x8*)&sXrT[tid * 64 + ((r8 ^ sw) * 8)] = p;
    }
    Rb[(size_t)g * RDIM + half * 256 + tid] = (bf16)(r0 * (1.f / 64.f));
    __syncthreads();

    #pragma unroll
    for (int nt = 0; nt < 4; ++nt) {
        int cl = wave * 64 + nt * 16 + (lane & 15);     // 0..255
        floatx4 acc[4] = {};
        #pragma unroll
        for (int kk = 0; kk < 2; ++kk) {
            bf16x8 bfrag = *(const bf16x8*)&sXrT[cl * 64 + (((kk * 4 + q) ^ (cl & 7)) * 8)];
            #pragma unroll
            for (int mt = 0; mt < 4; ++mt)
                acc[mt] = __builtin_amdgcn_mfma_f32_16x16x32_bf16(af[mt][kk], bfrag, acc[mt], 0, 0, 0);
        }
        #pragma unroll
        for (int mt = 0; mt < 4; ++mt)
            #pragma unroll
            for (int i = 0; i < 4; ++i)
                sOut[(mt * 16 + q * 4 + i) * 264 + cl] = (bf16)acc[mt][i];
    }
    __syncthreads();
    #pragma unroll
    for (int it = 0; it < 8; ++it) {
        int idx = it * 256 + tid;
        int d = idx >> 5, c8 = idx & 31;
        *(bf16x8*)&axs1[(size_t)(g * 64 + d) * IN_FEATS + half * 256 + c8 * 8] =
            *(const bf16x8*)&sOut[d * 264 + c8 * 8];
    }
}

// ============================ fused GEMM1 + GN1 + GEMM2 + agg + GN2 ==========
// v6: LDS cut to exactly 80 KiB for 2 blocks/CU.
//  - BK=32, 3 bufs x 8192 el (A 4096 + B 4096), counted vmcnt(2) depth-2.
//  - sX: [128][128] XOR-swizzled (group g at (g ^ (r&15))), no pad.
//  - so-scaling moved to the epilogue via (so.Y)@W2 = so.(Y@W2) (commutes),
//    eliminating the sSo LDS array.
//  - W2 slice staged per ct in two 32-KB halves into bufs 0..1; loads issued
//    before GN1 math so GN1 hides the drain.
// LDS map (40960 el = 81920 B):
//   buf b at b*8192 (b=0,1,2); sX at 24576.
//   epilogue: sT [256][136] = 34816 el at base (all prior data dead).
__global__ __launch_bounds__(512) void k_gemm12(
    const bf16* __restrict__ A, const bf16* __restrict__ BT1,
    const bf16* __restrict__ BT2, const bf16* __restrict__ adjb,
    const float* __restrict__ al1, const float* __restrict__ ga1, const float* __restrict__ be1,
    const float* __restrict__ al2, const float* __restrict__ ga2, const float* __restrict__ be2,
    const float* __restrict__ so, bf16* __restrict__ Rb)
{
    __shared__ __align__(16) bf16 sm[40960];
    const int tid = threadIdx.x;
    const int lane = tid & 63, wave = tid >> 6, q = lane >> 4;
    const int wm = wave >> 2, wn = wave & 3;
    const int by = blockIdx.x;
    const int row0 = by * 128;
    const int gw = by * 2 + wm;

    floatx4 acc2[4][4] = {};
    bf16* sX = sm + 24576;

    // staging helpers -------------------------------------------------------
    auto stage_ab = [&](int k0, int buf, int ct) {   // 2 vm-insts per thread
        int u = tid * 8;                 // 4096 el per half
        int r = u >> 5;                  // 0..127
        int cg = (u >> 3) & 3;
        int cs = cg ^ (r & 3);
        GLDS16(A   + (size_t)(row0 + r) * IN_FEATS + k0 + cs * 8,
               sm + buf * 8192 + u);
        GLDS16(BT1 + (size_t)(ct * 128 + r) * IN_FEATS + k0 + cs * 8,
               sm + buf * 8192 + 4096 + u);
    };
    auto stage_w2h = [&](int ct, int h) {            // 4 vm-insts per thread
        #pragma unroll
        for (int i = 0; i < 4; ++i) {
            int u = i * 4096 + tid * 8;  // 16384 el = [256][64]
            int rr = u >> 6;             // 0..255
            int cg = (u >> 3) & 7;
            int cs = cg ^ (rr & 7);
            GLDS16(BT2 + (size_t)rr * HIDDEN + ct * 128 + h * 64 + cs * 8,
                   sm + u);
        }
    };

    #pragma unroll 1
    for (int ct = 0; ct < 8; ++ct) {
        floatx4 acc1[4][2] = {};

        auto mfma_step = [&](int buf) {
            const bf16* sA = sm + buf * 8192;
            const bf16* sB = sA + 4096;
            bf16x8 afr[4], bfr[2];
            #pragma unroll
            for (int mt = 0; mt < 4; ++mt) {
                int r = wm * 64 + mt * 16 + (lane & 15);
                afr[mt] = *(const bf16x8*)&sA[r * 32 + ((q ^ (r & 3)) * 8)];
            }
            #pragma unroll
            for (int nt = 0; nt < 2; ++nt) {
                int r = wn * 32 + nt * 16 + (lane & 15);
                bfr[nt] = *(const bf16x8*)&sB[r * 32 + ((q ^ (r & 3)) * 8)];
            }
            #pragma unroll
            for (int mt = 0; mt < 4; ++mt)
                #pragma unroll
                for (int nt = 0; nt < 2; ++nt)
                    acc1[mt][nt] = __builtin_amdgcn_mfma_f32_16x16x32_bf16(
                        afr[mt], bfr[nt], acc1[mt][nt], 0, 0, 0);
        };

        // ---- prologue: two stages in flight
        stage_ab(0, 0, ct);
        stage_ab(32, 1, ct);

        // ---- counted-vmcnt pipelined K-loop (16 steps, depth 2, 3 bufs)
        #pragma unroll
        for (int t = 0; t < 16; ++t) {
            if (t < 15) { asm volatile("s_waitcnt vmcnt(2)" ::: "memory"); }
            else        { asm volatile("s_waitcnt vmcnt(0)" ::: "memory"); }
            __builtin_amdgcn_s_barrier();
            if (t < 14) stage_ab((t + 2) * 32, (t + 2) % 3, ct);
            mfma_step(t % 3);
        }
        __syncthreads();                 // all waves done with bufs before W2

        // ---- W2 half0 loads fly under GN1 math
        stage_w2h(ct, 0);

        // ---- GraphNorm1 + leaky + r1 + xs2 tile (UNSCALED) -> sX (swizzled)
        #pragma unroll
        for (int nt = 0; nt < 2; ++nt) {
            int cl = wn * 32 + nt * 16 + (lane & 15);
            int colg = ct * 128 + cl;
            float lsum = 0.f;
            #pragma unroll
            for (int mt = 0; mt < 4; ++mt)
                #pragma unroll
                for (int i = 0; i < 4; ++i) lsum += acc1[mt][nt][i];
            lsum += __shfl_xor(lsum, 16);
            lsum += __shfl_xor(lsum, 32);
            float am = al1[colg] * (lsum * (1.f / 64.f));
            float gm = ga1[colg], bt = be1[colg];
            float sub[4][4], qv = 0.f;
            #pragma unroll
            for (int mt = 0; mt < 4; ++mt)
                #pragma unroll
                for (int i = 0; i < 4; ++i) {
                    float d = acc1[mt][nt][i] - am;
                    sub[mt][i] = d; qv += d * d;
                }
            qv += __shfl_xor(qv, 16);
            qv += __shfl_xor(qv, 32);
            float rs = rsqrtf(qv * (1.f / 64.f) + EPS_F);
            float rsum = 0.f;
            int cg = cl >> 3, c7 = cl & 7;
            #pragma unroll
            for (int mt = 0; mt < 4; ++mt)
                #pragma unroll
                for (int i = 0; i < 4; ++i) {
                    float o = gm * sub[mt][i] * rs + bt;
                    o = (o >= 0.f) ? o : SLOPE_F * o;
                    rsum += o;
                    int r = wm * 64 + mt * 16 + q * 4 + i;
                    sX[r * 128 + ((cg ^ (r & 15)) * 8 + c7)] = (bf16)o;
                }
            rsum += __shfl_xor(rsum, 16);
            rsum += __shfl_xor(rsum, 32);
            if (lane < 16)
                Rb[(size_t)gw * RDIM + 512 + colg] = (bf16)(rsum * (1.f / 64.f));
        }
        asm volatile("s_waitcnt vmcnt(0)" ::: "memory");   // W2 half0 landed
        __syncthreads();                                   // sX + W2h0 visible

        // ---- GEMM2 accumulate over k-halves of this ct slice
        #pragma unroll
        for (int h = 0; h < 2; ++h) {
            if (h == 1) {
                __builtin_amdgcn_s_barrier();              // done reading h0
                stage_w2h(ct, 1);
                asm volatile("s_waitcnt vmcnt(0)" ::: "memory");
                __builtin_amdgcn_s_barrier();
            }
            #pragma unroll
            for (int kkh = 0; kkh < 2; ++kkh) {
                int kk2 = h * 2 + kkh;
                bf16x8 afr[4], bfr[4];
                #pragma unroll
                for (int mt = 0; mt < 4; ++mt) {
                    int r = wm * 64 + mt * 16 + (lane & 15);
                    afr[mt] = *(const bf16x8*)&sX[r * 128 + (((kk2 * 4 + q) ^ (r & 15)) * 8)];
                }
                #pragma unroll
                for (int nt = 0; nt < 4; ++nt) {
                    int r = wn * 64 + nt * 16 + (lane & 15);
                    bfr[nt] = *(const bf16x8*)&sm[r * 64 + (((kkh * 4 + q) ^ (r & 7)) * 8)];
                }
                #pragma unroll
                for (int mt = 0; mt < 4; ++mt)
                    #pragma unroll
                    for (int nt = 0; nt < 4; ++nt)
                        acc2[mt][nt] = __builtin_amdgcn_mfma_f32_16x16x32_bf16(
                            afr[mt], bfr[nt], acc2[mt][nt], 0, 0, 0);
            }
        }
        __syncthreads();                 // protect bufs/sX before next ct
    }

    // ---- epilogue: so-scale + in-LDS transpose + adj agg + GN2 + r2
    float sov[4][4];
    #pragma unroll
    for (int mt = 0; mt < 4; ++mt)
        #pragma unroll
        for (int i = 0; i < 4; ++i)
            sov[mt][i] = so[row0 + wm * 64 + mt * 16 + q * 4 + i];

    bf16* sT = sm;                       // [256 ch][136 pitch], wave-local quads
    #pragma unroll
    for (int nt = 0; nt < 4; ++nt) {
        int cl = wn * 64 + nt * 16 + (lane & 15);
        #pragma unroll
        for (int mt = 0; mt < 4; ++mt)
            #pragma unroll
            for (int i = 0; i < 4; ++i)
                sT[cl * 136 + wm * 64 + mt * 16 + q * 4 + i] =
                    (bf16)(acc2[mt][nt][i] * sov[mt][i]);
    }
    asm volatile("s_waitcnt lgkmcnt(0)" ::: "memory");   // wave-local LDS RAW

    const bf16* ag = adjb + ((size_t)gw << 12);
    floatx4 hh[4][4] = {};
    #pragma unroll
    for (int kk = 0; kk < 2; ++kk) {
        bf16x8 afr[4], bfr[4];
        #pragma unroll
        for (int mt = 0; mt < 4; ++mt)
            afr[mt] = *(const bf16x8*)&ag[(mt * 16 + (lane & 15)) * 64 + kk * 32 + q * 8];
        #pragma unroll
        for (int nt = 0; nt < 4; ++nt)
            bfr[nt] = *(const bf16x8*)&sT[(wn * 64 + nt * 16 + (lane & 15)) * 136 + wm * 64 + kk * 32 + q * 8];
        #pragma unroll
        for (int mt = 0; mt < 4; ++mt)
            #pragma unroll
            for (int nt = 0; nt < 4; ++nt)
                hh[mt][nt] = __builtin_amdgcn_mfma_f32_16x16x32_bf16(afr[mt], bfr[nt], hh[mt][nt], 0, 0, 0);
    }

    #pragma unroll
    for (int nt = 0; nt < 4; ++nt) {
        int colg = wn * 64 + nt * 16 + (lane & 15);
        float lsum = 0.f;
        #pragma unroll
        for (int mt = 0; mt < 4; ++mt)
            #pragma unroll
            for (int i = 0; i < 4; ++i) lsum += hh[mt][nt][i];
        lsum += __shfl_xor(lsum, 16);
        lsum += __shfl_xor(lsum, 32);
        float am = al2[colg] * (lsum * (1.f / 64.f));
        float gm = ga2[colg], bt = be2[colg];
        float sub[4][4], qv = 0.f;
        #pragma unroll
        for (int mt = 0; mt < 4; ++mt)
            #pragma unroll
            for (int i = 0; i < 4; ++i) {
                float d = hh[mt][nt][i] - am;
                sub[mt][i] = d; qv += d * d;
            }
        qv += __shfl_xor(qv, 16);
        qv += __shfl_xor(qv, 32);
        float rs = rsqrtf(qv * (1.f / 64.f) + EPS_F);
        float rsum = 0.f;
        #pragma unroll
        for (int mt = 0; mt < 4; ++mt)
            #pragma unroll
            for (int i = 0; i < 4; ++i) {
                float o = gm * sub[mt][i] * rs + bt;
                rsum += (o >= 0.f) ? o : SLOPE_F * o;
            }
        rsum += __shfl_xor(rsum, 16);
        rsum += __shfl_xor(rsum, 32);
        if (lane < 16)
            Rb[(size_t)gw * RDIM + 1536 + colg] = (bf16)(rsum * (1.f / 64.f));
    }
}

__device__ __forceinline__ void swizzle_block(int cb, int& bx, int& by)
{
    int b = blockIdx.y * gridDim.x + blockIdx.x;
    int xcd = b & 7, t = b >> 3;
    bx = t % cb;
    by = (t / cb) * 8 + xcd;
}

// --------------------- readout GEMM (fp32 C), T4 counted-vmcnt depth-3 loop
__global__ __launch_bounds__(256) void k_gemm_ro(
    const bf16* __restrict__ A, const bf16* __restrict__ BT,
    float* __restrict__ Cout)
{
    __shared__ __align__(16) bf16 sm[65536];   // 4 bufs x 16384 el
    const int tid = threadIdx.x;
    const int lane = tid & 63, wave = tid >> 6, q = lane >> 4;
    const int wm = wave & 1, wn = wave >> 1;
    int bx, by; swizzle_block(gridDim.x, bx, by);
    const int row0 = by * 128, col0 = bx * 128;

    floatx4 acc[4][4] = {};

    auto stage = [&](int k0, int buf) {
        #pragma unroll
        for (int i = 0; i < 4; ++i) {
            int u = (wave * 4 + i) * 64 + lane;
            int r = u >> 3, c = (u & 7) ^ (r & 7);
            GLDS16(A  + (size_t)(row0 + r) * RDIM + (k0 + c * 8),
                   sm + buf * 16384 + (wave * 4 + i) * 512);
            GLDS16(BT + (size_t)(col0 + r) * RDIM + (k0 + c * 8),
                   sm + buf * 16384 + 8192 + (wave * 4 + i) * 512);
        }
    };
    auto step = [&](int buf) {
        const bf16* sA = sm + buf * 16384;
        const bf16* sB = sA + 8192;
        #pragma unroll
        for (int kk = 0; kk < 2; ++kk) {
            bf16x8 afr[4], bfr[4];
            int cw = kk * 4 + q;
            #pragma unroll
            for (int mt = 0; mt < 4; ++mt) {
                int r = wm * 64 + mt * 16 + (lane & 15);
                afr[mt] = *(const bf16x8*)&sA[(r * 8 + (cw ^ (r & 7))) * 8];
            }
            #pragma unroll
            for (int nt = 0; nt < 4; ++nt) {
                int r = wn * 64 + nt * 16 + (lane & 15);
                bfr[nt] = *(const bf16x8*)&sB[(r * 8 + (cw ^ (r & 7))) * 8];
            }
            #pragma unroll
            for (int mt = 0; mt < 4; ++mt)
                #pragma unroll
                for (int nt = 0; nt < 4; ++nt)
                    acc[mt][nt] = __builtin_amdgcn_mfma_f32_16x16x32_bf16(
                        afr[mt], bfr[nt], acc[mt][nt], 0, 0, 0);
        }
    };

    stage(0, 0); stage(64, 1); stage(128, 2);
    #pragma unroll 1
    for (int t = 0; t < 26; ++t) {
        asm volatile("s_waitcnt vmcnt(16)" ::: "memory");
        __builtin_amdgcn_s_barrier();
        if (t < 25) stage((t + 3) * 64, (t + 3) & 3);
        step(t & 3);
    }
    asm volatile("s_waitcnt vmcnt(8)" ::: "memory");
    __builtin_amdgcn_s_barrier();
    step(2);
    asm volatile("s_waitcnt vmcnt(0)" ::: "memory");
    __builtin_amdgcn_s_barrier();
    step(3);

    #pragma unroll
    for (int mt = 0; mt < 4; ++mt)
        #pragma unroll
        for (int nt = 0; nt < 4; ++nt) {
            int col = col0 + wn * 64 + nt * 16 + (lane & 15);
            #pragma unroll
            for (int i = 0; i < 4; ++i) {
                int row = row0 + wm * 64 + mt * 16 + q * 4 + i;
                Cout[(size_t)row * EMB_DIM + col] = acc[mt][nt][i];
            }
        }
}

// ------------------------------------------------------- InstanceNorm + leaky
__global__ __launch_bounds__(256) void k_instnorm(
    const float* __restrict__ emb, float* __restrict__ out)
{
    int row = blockIdx.x, tid = threadIdx.x;
    int lane = tid & 63, wave = tid >> 6;
    __shared__ float sS[4], sQ[4];
    float v0 = emb[(size_t)row * EMB_DIM + tid];
    float v1 = emb[(size_t)row * EMB_DIM + 256 + tid];
    float s = v0 + v1, q = v0 * v0 + v1 * v1;
    #pragma unroll
    for (int off = 32; off; off >>= 1) {
        s += __shfl_down(s, off);
        q += __shfl_down(q, off);
    }
    if (lane == 0) { sS[wave] = s; sQ[wave] = q; }
    __syncthreads();
    float S = sS[0] + sS[1] + sS[2] + sS[3];
    float Q = sQ[0] + sQ[1] + sQ[2] + sQ[3];
    float mu = S * (1.f / 512.f);
    float var = Q * (1.f / 512.f) - mu * mu;
    float rs = rsqrtf(var + EPS_F);
    float o0 = (v0 - mu) * rs; o0 = (o0 >= 0.f) ? o0 : SLOPE_F * o0;
    float o1 = (v1 - mu) * rs; o1 = (o1 >= 0.f) ? o1 : SLOPE_F * o1;
    out[(size_t)row * EMB_DIM + tid]       = o0;
    out[(size_t)row * EMB_DIM + 256 + tid] = o1;
}

// ----------------------------------------------------------------- launcher
extern "C" void kernel_launch(void* const* d_in, const int* in_sizes, int n_in,
                              void* d_out, int out_size, void* d_ws, size_t ws_size,
                              hipStream_t stream) {
    const float* x    = (const float*)d_in[0];
    const float* ew   = (const float*)d_in[1];
    const float* W1   = (const float*)d_in[2];
    const float* W2   = (const float*)d_in[3];
    const float* Wemb = (const float*)d_in[4];
    const float* a1   = (const float*)d_in[5];
    const float* g1   = (const float*)d_in[6];
    const float* b1   = (const float*)d_in[7];
    const float* a2   = (const float*)d_in[8];
    const float* g2   = (const float*)d_in[9];
    const float* b2   = (const float*)d_in[10];
    const int* esrc   = (const int*)d_in[11];
    const int* edst   = (const int*)d_in[12];
    float* out = (float*)d_out;

    char* ws = (char*)d_ws;
    const size_t MB = 1024ull * 1024ull;
    bf16*  adjb   = (bf16*)(ws);                       // 8 MB
    float* scl_o  = (float*)(ws + 8 * MB);             // 256 KB
    bf16*  Rb     = (bf16*)(ws + 9 * MB);              // 3.5 MB
    bf16*  W1T    = (bf16*)(ws + 13 * MB);             // 1 MB
    bf16*  W2T    = (bf16*)(ws + 14 * MB);             // 0.5 MB
    bf16*  WembT  = (bf16*)(ws + 15 * MB);             // 1.75 MB
    float* emb    = (float*)(ws + 17 * MB);            // 2 MB
    bf16*  axs1   = (bf16*)(ws + 20 * MB);             // 64 MB

    k_graph_build<<<N_GRAPHS, 256, 0, stream>>>(esrc, edst, ew, adjb, scl_o);
    k_transpose3<<<416, 256, 0, stream>>>(W1, W1T, W2, W2T, Wemb, WembT);

    k_prep_agg1<<<N_GRAPHS * 2, 256, 0, stream>>>(x, scl_o, adjb, axs1, Rb);

    k_gemm12<<<N_NODES / 128, 512, 0, stream>>>(
        axs1, W1T, W2T, adjb, a1, g1, b1, a2, g2, b2, scl_o, Rb);

    k_gemm_ro<<<dim3(EMB_DIM / 128, N_GRAPHS / 128), 256, 0, stream>>>(
        Rb, WembT, emb);
    k_instnorm<<<N_GRAPHS, 256, 0, stream>>>(emb, out);

    (void)in_sizes; (void)n_in; (void)out_size; (void)ws_size;
}